// Round 2
// baseline (3865.723 us; speedup 1.0000x reference)
//
#include <hip/hip_runtime.h>
#include <cstdint>
#include <cstddef>

// ===========================================================================
// QLSTMHybrid: LSTM (S=1024,B=256,D=128,H=256) + attention pooling (A=256)
//
// Plan:
//   k_pack  : repack Wf/Wi/Wg/Wo/Wa fp32 -> packed f16x2 (ws)
//   k_xproj : xproj[s,b,c] = x[s,b,:] @ Wx[:,c] + bias[c]   (f16, ws, 537MB)
//             c in [0,1024): gate-major, gate=c>>8 (f,i,g,o), unit=c&255
//   k_recur : persistent, 256 WGs (1 per batch elem b, 1 per CU), 512 thr.
//             Wh (256x1024 f16 = 512KB) resident per CU:
//               pairs 0..95  -> VGPRs (2 cols/thread x 96 = 192 regs)
//               pairs 96..127-> LDS   (1024 cols x 32 pairs, stride 36 dw)
//             per step: preact[c] = xproj + sum_k h[k]*Wh[k][c] via
//             v_dot2_f32_f16; epilogue (threads<256) does gates/c/h;
//             h written f16 into d_out-as-f16 ("oseq") + final hx/cx fp32.
//   k_attn  : per b: online softmax over s of (h_row @ Wa + ba), elementwise
//             context accumulate -> ctx[b][a] (ws)
//   k_bcast : d_out[s,b,h] = ctx[b,h] (overwrites the oseq scratch region)
//             !! 16,777,216 float4 needed -> 65536 blocks x 256 thr
//             (round-1 bug: only 1/4 of output 0 was written; absmax equaled
//              the stub's max|ctx| = 2.368e-2 because 3/4 stayed ~0)
//
// ws layout (bytes):            needs ws_size >= 538,050,560
#define WS_WHP   0           // uint32[128][1024]  524288
#define WS_WXP   524288      // uint32[64][1024]   262144
#define WS_WAP   786432      // uint32[128][256]   131072
#define WS_CTX   917504      // float [65536]      262144
#define WS_XPROJ 1179648     // f16   [262144][1024] 536870912
// ===========================================================================

typedef _Float16 h2_t __attribute__((ext_vector_type(2)));

static __device__ __forceinline__ float fdot2(uint32_t a, uint32_t b, float acc) {
#if __has_builtin(__builtin_amdgcn_fdot2)
    return __builtin_amdgcn_fdot2(__builtin_bit_cast(h2_t, a),
                                  __builtin_bit_cast(h2_t, b), acc, false);
#else
    union { uint32_t u; _Float16 f[2]; } ua, ub;
    ua.u = a; ub.u = b;
    return acc + (float)ua.f[0] * (float)ub.f[0] + (float)ua.f[1] * (float)ub.f[1];
#endif
}

static __device__ __forceinline__ uint32_t packh2(float x, float y) {
    h2_t v; v[0] = (_Float16)x; v[1] = (_Float16)y;
    return __builtin_bit_cast(uint32_t, v);
}
static __device__ __forceinline__ uint16_t f16b(float v) {
    _Float16 h = (_Float16)v; return __builtin_bit_cast(uint16_t, h);
}
static __device__ __forceinline__ float h16tof(uint16_t u) {
    return (float)__builtin_bit_cast(_Float16, u);
}
static __device__ __forceinline__ float sigm(float x) {
    return 1.0f / (1.0f + __expf(-x));
}
static __device__ __forceinline__ float tanh_fast(float x) {
    float ax = fabsf(x);
    float e = __expf(-2.0f * ax);           // underflows to 0 for large ax -> r=1
    float r = (1.0f - e) / (1.0f + e);
    return (x < 0.0f) ? -r : r;
}

// ---------------------------------------------------------------- k_pack ---
__global__ void k_pack(const float* __restrict__ Wf, const float* __restrict__ Wi,
                       const float* __restrict__ Wg2, const float* __restrict__ Wo,
                       const float* __restrict__ Wa,
                       uint32_t* __restrict__ whp, uint32_t* __restrict__ wxp,
                       uint32_t* __restrict__ wap) {
    int idx = blockIdx.x * 256 + threadIdx.x;
    if (idx < 131072) {                       // Wh pairs: rows 128..383 of W*
        int p = idx >> 10, c = idx & 1023;
        int g = c >> 8, u = c & 255;
        const float* W = (g == 0) ? Wf : (g == 1) ? Wi : (g == 2) ? Wg2 : Wo;
        whp[idx] = packh2(W[(128 + 2 * p) * 256 + u], W[(129 + 2 * p) * 256 + u]);
    } else if (idx < 196608) {                // Wx pairs: rows 0..127
        int j = idx - 131072;
        int p = j >> 10, c = j & 1023;
        int g = c >> 8, u = c & 255;
        const float* W = (g == 0) ? Wf : (g == 1) ? Wi : (g == 2) ? Wg2 : Wo;
        wxp[j] = packh2(W[(2 * p) * 256 + u], W[(2 * p + 1) * 256 + u]);
    } else if (idx < 229376) {                // Wa pairs
        int j = idx - 196608;
        int p = j >> 8, aa = j & 255;
        wap[j] = packh2(Wa[(2 * p) * 256 + aa], Wa[(2 * p + 1) * 256 + aa]);
    }
}

// --------------------------------------------------------------- k_xproj ---
// grid 2048 x 512; each WG does 128 rows of (262144 x 128) @ (128 x 1024)
__global__ __launch_bounds__(512) void k_xproj(
        const float* __restrict__ x,
        const float* __restrict__ bfp, const float* __restrict__ bip,
        const float* __restrict__ bgp, const float* __restrict__ bop,
        const uint32_t* __restrict__ wxp, uint16_t* __restrict__ xproj) {
    __shared__ uint32_t xs[512];              // 8 rows x 64 pairs
    int t = threadIdx.x;
    int c0 = t, c1 = t + 512;
    uint32_t wx0[64], wx1[64];
#pragma unroll
    for (int p = 0; p < 64; ++p) {
        wx0[p] = wxp[p * 1024 + c0];
        wx1[p] = wxp[p * 1024 + c1];
    }
    float bias0 = (t < 256) ? bfp[t] : bip[t - 256];   // cols 0..511  : f,i
    float bias1 = (t < 256) ? bgp[t] : bop[t - 256];   // cols 512..1023: g,o
    int srow = t >> 6, pp = t & 63;
    long row0 = (long)blockIdx.x * 128;
    for (int ch = 0; ch < 16; ++ch) {
        long rbase = row0 + ch * 8;
        const float2* xr = (const float2*)(x + (rbase + srow) * 128) + pp;
        float2 xv = *xr;
        __syncthreads();                      // prior chunk's reads done
        xs[srow * 64 + pp] = packh2(xv.x, xv.y);
        __syncthreads();
#pragma unroll 1
        for (int r = 0; r < 8; ++r) {
            const uint32_t* hrow = xs + r * 64;
            float a0 = 0.f, d0 = 0.f, a1 = 0.f, d1 = 0.f;
#pragma unroll
            for (int p = 0; p < 64; p += 4) {
                uint4 hv = *(const uint4*)(hrow + p);
                a0 = fdot2(wx0[p + 0], hv.x, a0); d0 = fdot2(wx0[p + 1], hv.y, d0);
                a0 = fdot2(wx0[p + 2], hv.z, a0); d0 = fdot2(wx0[p + 3], hv.w, d0);
                a1 = fdot2(wx1[p + 0], hv.x, a1); d1 = fdot2(wx1[p + 1], hv.y, d1);
                a1 = fdot2(wx1[p + 2], hv.z, a1); d1 = fdot2(wx1[p + 3], hv.w, d1);
            }
            size_t orow = (size_t)(rbase + r) * 1024;
            xproj[orow + c0] = f16b(a0 + d0 + bias0);
            xproj[orow + c1] = f16b(a1 + d1 + bias1);
        }
    }
}

// --------------------------------------------------------------- k_recur ---
// 256 WGs x 512 thr. WG b owns batch element b. Thread t owns cols t, t+512.
// LDS: wlds[1024 cols][36 dw stride] (pairs 96..127) + h2[128] + P[1024]
#define RECUR_LDS 152064

__global__ __launch_bounds__(512, 2) void k_recur(
        const uint32_t* __restrict__ whp, const uint16_t* __restrict__ xproj,
        const int* __restrict__ mask, uint16_t* __restrict__ oseq,
        float* __restrict__ dout) {
    extern __shared__ uint32_t smem[];
    uint32_t* wlds = smem;                    // 1024*36 = 36864 uints
    uint32_t* h2   = smem + 36864;            // 128 uints (256 f16)
    float*    P    = (float*)(smem + 36992);  // 1024 floats
    int t = threadIdx.x;
    int b = blockIdx.x;
    int c0 = t, c1 = t + 512;

    // stage LDS-resident weight pairs 96..127 for all 1024 cols
    for (int j = t; j < 32768; j += 512) {
        int c = j >> 5, pp = j & 31;
        wlds[c * 36 + pp] = whp[(96 + pp) * 1024 + c];
    }
    if (t < 128) h2[t] = 0u;                  // h = 0

    uint32_t w0[96], w1[96];                  // VGPR-resident pairs 0..95
#pragma unroll
    for (int p = 0; p < 96; ++p) {
        w0[p] = whp[p * 1024 + c0];
        w1[p] = whp[p * 1024 + c1];
    }
    float c_state = 0.f, h_state = 0.f;
    const uint16_t* xp_ptr = xproj + b * 1024;
    uint16_t* oseq_ptr = oseq + b * 256;
    uint16_t xv0 = xp_ptr[c0], xv1 = xp_ptr[c1];   // prefetch step 0
    int mv = mask[b];
    __syncthreads();

    for (int s = 0; s < 1024; ++s) {
        float xpf0 = h16tof(xv0), xpf1 = h16tof(xv1);
        float mcur = (float)mv;
        xp_ptr += 262144;
        if (s < 1023) {                       // prefetch step s+1
            xv0 = xp_ptr[c0]; xv1 = xp_ptr[c1];
            mv = mask[(s + 1) * 256 + b];
        }
        float a0 = 0.f, b0 = 0.f, a1 = 0.f, b1 = 0.f;
        // LDS-resident pairs 96..127 (8 uint4 chunks)
#pragma unroll
        for (int j = 0; j < 8; ++j) {
            uint4 hv = *(const uint4*)(h2 + 96 + j * 4);
            uint4 wA = *(const uint4*)(wlds + c0 * 36 + j * 4);
            uint4 wB = *(const uint4*)(wlds + c1 * 36 + j * 4);
            a0 = fdot2(wA.x, hv.x, a0); b0 = fdot2(wA.y, hv.y, b0);
            a0 = fdot2(wA.z, hv.z, a0); b0 = fdot2(wA.w, hv.w, b0);
            a1 = fdot2(wB.x, hv.x, a1); b1 = fdot2(wB.y, hv.y, b1);
            a1 = fdot2(wB.z, hv.z, a1); b1 = fdot2(wB.w, hv.w, b1);
        }
        // VGPR-resident pairs 0..95 (24 uint4 chunks)
#pragma unroll
        for (int j = 0; j < 24; ++j) {
            uint4 hv = *(const uint4*)(h2 + j * 4);
            a0 = fdot2(w0[4 * j + 0], hv.x, a0); b0 = fdot2(w0[4 * j + 1], hv.y, b0);
            a0 = fdot2(w0[4 * j + 2], hv.z, a0); b0 = fdot2(w0[4 * j + 3], hv.w, b0);
            a1 = fdot2(w1[4 * j + 0], hv.x, a1); b1 = fdot2(w1[4 * j + 1], hv.y, b1);
            a1 = fdot2(w1[4 * j + 2], hv.z, a1); b1 = fdot2(w1[4 * j + 3], hv.w, b1);
        }
        P[c0] = a0 + b0 + xpf0;
        P[c1] = a1 + b1 + xpf1;
        __syncthreads();
        if (t < 256) {
            float fg = sigm(P[t]);
            float ig = sigm(P[256 + t]);
            float gg = tanh_fast(P[512 + t]);
            float og = sigm(P[768 + t]);
            fg = fg * mcur + (1.0f - mcur);
            ig = ig * mcur;
            gg = gg * mcur;
            og = og * mcur + (1.0f - mcur);
            c_state = fg * c_state + ig * gg;
            h_state = og * tanh_fast(c_state);
            uint16_t hb = f16b(h_state);
            ((uint16_t*)h2)[t] = hb;          // h for next step (f16)
            oseq_ptr[t] = hb;                 // h sequence for attention
        }
        __syncthreads();
        oseq_ptr += 65536;
    }
    if (t < 256) {
        dout[67108864 + b * 256 + t] = h_state;   // hx
        dout[67174400 + b * 256 + t] = c_state;   // cx
    }
}

// ---------------------------------------------------------------- k_attn ---
// 256 WGs (one per b) x 256 thr (one per a). Online softmax over s.
__global__ __launch_bounds__(256) void k_attn(
        const uint32_t* __restrict__ wap, const float* __restrict__ ba,
        const uint16_t* __restrict__ oseq, float* __restrict__ ctx) {
    __shared__ uint32_t rb[2][128];
    int a = threadIdx.x, b = blockIdx.x;
    uint32_t wa[128];
#pragma unroll
    for (int p = 0; p < 128; ++p) wa[p] = wap[p * 256 + a];
    float bias = ba[a];
    const uint32_t* orow = (const uint32_t*)oseq + b * 128;  // row s at +s*32768
    if (a < 128) rb[0][a] = orow[a];
    __syncthreads();
    float m = -3.0e38f, Z = 0.f, acc = 0.f;
    for (int s = 0; s < 1024; ++s) {
        uint32_t nxt = 0;
        if (s < 1023 && a < 128) nxt = orow[32768 * (s + 1) + a];
        const uint32_t* row = rb[s & 1];
        float l0 = bias, l1 = 0.f, l2 = 0.f, l3 = 0.f;
#pragma unroll
        for (int p = 0; p < 128; p += 4) {
            uint4 hv = *(const uint4*)(row + p);
            l0 = fdot2(wa[p + 0], hv.x, l0);
            l1 = fdot2(wa[p + 1], hv.y, l1);
            l2 = fdot2(wa[p + 2], hv.z, l2);
            l3 = fdot2(wa[p + 3], hv.w, l3);
        }
        float l = (l0 + l1) + (l2 + l3);
        uint32_t pv = row[a >> 1];
        float hself = h16tof((a & 1) ? (uint16_t)(pv >> 16) : (uint16_t)(pv & 0xffffu));
        float m2 = fmaxf(m, l);
        float al = __expf(m - m2);
        float pr = __expf(l - m2);
        Z = Z * al + pr;
        acc = acc * al + pr * hself;
        m = m2;
        if (s < 1023 && a < 128) rb[(s + 1) & 1][a] = nxt;
        __syncthreads();
    }
    ctx[b * 256 + a] = acc / Z;
}

// --------------------------------------------------------------- k_bcast ---
// output 0 = 67,108,864 floats = 16,777,216 float4 -> 65536 blocks x 256 thr
__global__ void k_bcast(const float4* __restrict__ ctx4, float4* __restrict__ out4) {
    int i = blockIdx.x * 256 + threadIdx.x;
    out4[i] = ctx4[i & 16383];                // 16384 float4 per s-slice
}

// ===========================================================================
extern "C" void kernel_launch(void* const* d_in, const int* in_sizes, int n_in,
                              void* d_out, int out_size, void* d_ws, size_t ws_size,
                              hipStream_t stream) {
    const float* x    = (const float*)d_in[0];
    const int*   mask = (const int*)d_in[1];
    const float* Wf   = (const float*)d_in[2];
    const float* bf   = (const float*)d_in[3];
    const float* Wi   = (const float*)d_in[4];
    const float* bi   = (const float*)d_in[5];
    const float* Wg   = (const float*)d_in[6];
    const float* bg   = (const float*)d_in[7];
    const float* Wo   = (const float*)d_in[8];
    const float* bo   = (const float*)d_in[9];
    const float* Wa   = (const float*)d_in[10];
    const float* ba   = (const float*)d_in[11];
    float* out = (float*)d_out;
    char*  ws  = (char*)d_ws;

    uint32_t* whp   = (uint32_t*)(ws + WS_WHP);
    uint32_t* wxp   = (uint32_t*)(ws + WS_WXP);
    uint32_t* wap   = (uint32_t*)(ws + WS_WAP);
    float*    ctx   = (float*)(ws + WS_CTX);
    uint16_t* xproj = (uint16_t*)(ws + WS_XPROJ);
    uint16_t* oseq  = (uint16_t*)d_out;       // f16 h-seq scratch inside d_out
                                              // (overwritten later by k_bcast)

    (void)in_sizes; (void)n_in; (void)out_size; (void)ws_size;

    // allow >64KB dynamic LDS for the persistent recurrence kernel
    hipFuncSetAttribute((const void*)k_recur,
                        hipFuncAttributeMaxDynamicSharedMemorySize, RECUR_LDS);

    k_pack<<<896, 256, 0, stream>>>(Wf, Wi, Wg, Wo, Wa, whp, wxp, wap);
    k_xproj<<<2048, 512, 0, stream>>>(x, bf, bi, bg, bo, wxp, xproj);
    k_recur<<<256, 512, RECUR_LDS, stream>>>(whp, xproj, mask, oseq, out);
    k_attn<<<256, 256, 0, stream>>>(wap, ba, oseq, ctx);
    k_bcast<<<65536, 256, 0, stream>>>((const float4*)ctx, (float4*)out);
}